// Round 2
// baseline (162.975 us; speedup 1.0000x reference)
//
#include <hip/hip_runtime.h>
#include <hip/hip_bf16.h>
#include <stdint.h>

// Problem: B=4, C=64, N=16384, K=16, CO=64  (all float32 I/O, int32 indices)
// h[b,o,n,k] = y1[b,o,n] - y2[b,o,idx[b,n,k]]
//   y1 = (W1+W2) @ x, y2 = W2 @ x
// out[b,o,n] = leakyrelu(gamma*(sel - mean)*rsqrt(var+eps) + beta)
//   sel = max_k h if scale>=0 else min_k h (monotone transform commutes with max)

#define NB 4
#define CDIM 64
#define NDIM 16384
#define KNB 16
#define BNK_F 1048576.0f

union Pack4 { __hip_bfloat16 h[4]; uint2 u; };

// ---------------- Kernel 1: y1/y2 GEMM ----------------
// grid = B * (N/64) = 1024 blocks, 256 threads
__global__ __launch_bounds__(256) void gemm_y_kernel(
    const float* __restrict__ x,            // (B, C, N) fp32
    const float* __restrict__ W,            // (CO, 2C)  fp32
    __hip_bfloat16* __restrict__ y1,        // (B, N, CO) bf16
    __hip_bfloat16* __restrict__ y2)        // (B, N, CO) bf16
{
    __shared__ alignas(16) float Ws12[64 * 68];
    __shared__ alignas(16) float Ws2 [64 * 68];
    __shared__ alignas(16) float xs  [64 * 68];

    const int tid = threadIdx.x;
    const int b  = blockIdx.x >> 8;           // N/64 = 256 tiles per batch
    const int n0 = (blockIdx.x & 255) << 6;

    // stage W transposed: Ws[c][o]
    for (int i = tid; i < 4096; i += 256) {
        int o = i >> 6, c = i & 63;
        float w1 = W[o * 128 + c];
        float w2 = W[o * 128 + 64 + c];
        Ws12[c * 68 + o] = w1 + w2;
        Ws2 [c * 68 + o] = w2;
    }
    // stage x tile: xs[c][nl]
    const float* xb = x + (size_t)b * CDIM * NDIM + n0;
    for (int i = tid; i < 4096; i += 256) {
        int c = i >> 6, nl = i & 63;
        xs[c * 68 + nl] = xb[(size_t)c * NDIM + nl];
    }
    __syncthreads();

    const int o0  = (tid & 15) * 4;
    const int nl0 = (tid >> 4) * 4;
    float acc1[4][4] = {};
    float acc2[4][4] = {};

    #pragma unroll 4
    for (int c = 0; c < 64; ++c) {
        const float4 w12 = *(const float4*)&Ws12[c * 68 + o0];
        const float4 w2v = *(const float4*)&Ws2 [c * 68 + o0];
        const float4 xv  = *(const float4*)&xs  [c * 68 + nl0];
        const float xa[4] = { xv.x,  xv.y,  xv.z,  xv.w  };
        const float wa[4] = { w12.x, w12.y, w12.z, w12.w };
        const float wb[4] = { w2v.x, w2v.y, w2v.z, w2v.w };
        #pragma unroll
        for (int i = 0; i < 4; ++i) {
            #pragma unroll
            for (int j = 0; j < 4; ++j) {
                acc1[i][j] = fmaf(wa[j], xa[i], acc1[i][j]);
                acc2[i][j] = fmaf(wb[j], xa[i], acc2[i][j]);
            }
        }
    }

    const size_t bn0 = (size_t)b * NDIM + n0;
    #pragma unroll
    for (int i = 0; i < 4; ++i) {
        Pack4 p1, p2;
        #pragma unroll
        for (int j = 0; j < 4; ++j) {
            p1.h[j] = __float2bfloat16(acc1[i][j]);
            p2.h[j] = __float2bfloat16(acc2[i][j]);
        }
        size_t off = (bn0 + nl0 + i) * 64 + o0;
        *(uint2*)(y1 + off) = p1.u;
        *(uint2*)(y2 + off) = p2.u;
    }
}

// ---------------- Kernel 2: gather + max/min + BN partial stats ----------------
// one wave handles one (b,n) per iteration; lane = output channel o
__global__ __launch_bounds__(256) void gather_stats_kernel(
    const __hip_bfloat16* __restrict__ y1,
    const __hip_bfloat16* __restrict__ y2,
    const int* __restrict__ ei,              // (B, N, K) int32
    const float* __restrict__ gamma,
    float* __restrict__ hsel,                // (B, N, CO) fp32
    float* __restrict__ stats,               // [0..63]=sum, [64..127]=sumsq
    int nwavetot)
{
    const int lane = threadIdx.x & 63;
    const int widx = threadIdx.x >> 6;
    const int gw   = blockIdx.x * 4 + widx;

    const float g = gamma[lane];
    const bool useMax = (g >= 0.0f);

    float ssum = 0.0f, ssq = 0.0f;

    for (int bn = gw; bn < NB * NDIM; bn += nwavetot) {
        const int bnu = __builtin_amdgcn_readfirstlane(bn);
        const int b = bnu >> 14;
        const float y1v = __bfloat162float(y1[(size_t)bnu * 64 + lane]);
        const int* row = ei + (size_t)bnu * KNB;
        const __hip_bfloat16* y2b = y2 + ((size_t)b << 14) * 64;

        float hmax = -3.402823e38f, hmin = 3.402823e38f;
        #pragma unroll
        for (int k = 0; k < KNB; ++k) {
            int j = row[k];
            float y2v = __bfloat162float(y2b[(size_t)j * 64 + lane]);
            float h = y1v - y2v;
            ssum += h;
            ssq  = fmaf(h, h, ssq);
            hmax = fmaxf(hmax, h);
            hmin = fminf(hmin, h);
        }
        hsel[(size_t)bnu * 64 + lane] = useMax ? hmax : hmin;
    }

    __shared__ float rs[4][64];
    __shared__ float rq[4][64];
    rs[widx][lane] = ssum;
    rq[widx][lane] = ssq;
    __syncthreads();
    if (threadIdx.x < 64) {
        float s = rs[0][lane] + rs[1][lane] + rs[2][lane] + rs[3][lane];
        float q = rq[0][lane] + rq[1][lane] + rq[2][lane] + rq[3][lane];
        atomicAdd(&stats[lane], s);
        atomicAdd(&stats[64 + lane], q);
    }
}

// ---------------- Kernel 3: finalize BN params ----------------
__global__ void finalize_kernel(
    const float* __restrict__ stats,
    const float* __restrict__ gamma,
    const float* __restrict__ beta,
    float* __restrict__ sb)                  // [0..63]=scale, [64..127]=bias
{
    int t = threadIdx.x;   // 64 threads
    float mean = stats[t] * (1.0f / BNK_F);
    float var  = stats[64 + t] * (1.0f / BNK_F) - mean * mean;
    float g  = gamma[t];
    float be = beta[t];
    float scale = g * rsqrtf(var + 1e-5f);
    sb[t]      = scale;
    sb[64 + t] = be - mean * scale;
}

// ---------------- Kernel 4: transpose + affine + leaky + store ----------------
// grid = B * (N/64) = 1024 blocks, 256 threads
__global__ __launch_bounds__(256) void out_kernel(
    const float* __restrict__ hsel,          // (B, N, CO)
    const float* __restrict__ sb,
    float* __restrict__ out)                 // (B, CO, N) fp32
{
    __shared__ float tile[64 * 65];
    const int b  = blockIdx.x >> 8;
    const int n0 = (blockIdx.x & 255) << 6;
    const int lane = threadIdx.x & 63;
    const size_t bn0 = (size_t)b * NDIM + n0;

    for (int nl = (int)(threadIdx.x >> 6); nl < 64; nl += 4)
        tile[nl * 65 + lane] = hsel[(bn0 + nl) * 64 + lane];
    __syncthreads();

    for (int o = (int)(threadIdx.x >> 6); o < 64; o += 4) {
        float s  = sb[o];
        float bi = sb[64 + o];
        float v = fmaf(s, tile[lane * 65 + o], bi);
        v = (v >= 0.0f) ? v : 0.2f * v;
        out[((size_t)(b * 64 + o) << 14) + n0 + lane] = v;
    }
}

extern "C" void kernel_launch(void* const* d_in, const int* in_sizes, int n_in,
                              void* d_out, int out_size, void* d_ws, size_t ws_size,
                              hipStream_t stream) {
    const float* x     = (const float*)d_in[0];
    const int*   ei    = (const int*)d_in[1];
    const float* W     = (const float*)d_in[2];
    const float* gamma = (const float*)d_in[3];
    const float* beta  = (const float*)d_in[4];
    float* out = (float*)d_out;

    char* ws = (char*)d_ws;
    // layout: y1 bf16 8 MiB | y2 bf16 8 MiB | hsel fp32 16 MiB | stats | sb
    __hip_bfloat16* y1   = (__hip_bfloat16*)(ws);
    __hip_bfloat16* y2   = (__hip_bfloat16*)(ws + 8388608);
    float*          hsel = (float*)(ws + 16777216);
    float*          stats= (float*)(ws + 33554432);
    float*          sb   = (float*)(ws + 33554432 + 512);

    hipMemsetAsync(stats, 0, 512, stream);

    gemm_y_kernel<<<dim3(NB * (NDIM / 64)), dim3(256), 0, stream>>>(x, W, y1, y2);
    gather_stats_kernel<<<dim3(2048), dim3(256), 0, stream>>>(y1, y2, ei, gamma, hsel, stats, 2048 * 4);
    finalize_kernel<<<dim3(1), dim3(64), 0, stream>>>(stats, gamma, beta, sb);
    out_kernel<<<dim3(NB * (NDIM / 64)), dim3(256), 0, stream>>>(hsel, sb, out);
}